// Round 2
// baseline (618.501 us; speedup 1.0000x reference)
//
#include <hip/hip_runtime.h>

typedef unsigned short u16;
typedef unsigned int u32;
typedef __bf16 bf16x8 __attribute__((ext_vector_type(8)));
typedef float f32x4 __attribute__((ext_vector_type(4)));
typedef u32 u32x2 __attribute__((ext_vector_type(2)));

// B=65536, I=64, H=64, T=16, G=3H=192. Block = 64 rows, 256 threads, grid 1024.

__device__ __forceinline__ u16 f2bf(float f) {
  union { float f; u32 u; } v; v.f = f;
  u32 u = v.u;
  return (u16)((u + 0x7fffu + ((u >> 16) & 1u)) >> 16);  // RNE
}
__device__ __forceinline__ float bf2f(u16 h) {
  union { u32 u; float f; } v; v.u = ((u32)h) << 16;
  return v.f;
}
__device__ __forceinline__ u32 pack2(float a, float b) {
  return (u32)f2bf(a) | ((u32)f2bf(b) << 16);
}
__device__ __forceinline__ bf16x8 pack8(float4 a, float4 b) {
  union { u32 u[4]; bf16x8 v; } r;
  r.u[0] = pack2(a.x, a.y); r.u[1] = pack2(a.z, a.w);
  r.u[2] = pack2(b.x, b.y); r.u[3] = pack2(b.z, b.w);
  return r.v;
}
__device__ __forceinline__ float sigf(float x) { return 1.0f / (1.0f + __expf(-x)); }
__device__ __forceinline__ float tanh_fast(float x) { return 2.0f * sigf(2.0f * x) - 1.0f; }

// ---------------- K0: convert weights fp32 -> bf16 ----------------
__global__ __launch_bounds__(256) void k0_convert(
    const float* __restrict__ Wih, const float* __restrict__ Whh,
    const float* __restrict__ cWih, const float* __restrict__ cWhh,
    u16* __restrict__ wih_bf, u16* __restrict__ whh_bf,
    u16* __restrict__ cwih_bf, u16* __restrict__ cwhh_bf)
{
  int i = blockIdx.x * 256 + threadIdx.x;
  if (i < 196608) {          // 16*192*64 and 192*1024
    wih_bf[i]  = f2bf(Wih[i]);
    whh_bf[i]  = f2bf(Whh[i]);
    cwih_bf[i] = f2bf(cWih[i]);
  }
  if (i < 12288) cwhh_bf[i] = f2bf(cWhh[i]);  // 192*64
}

// ---------------- KF: fully fused ----------------
#define SA 1040   // u16 stride of A-tile row (2080 B, 16B-aligned)
#define SH 72     // u16 stride of hnew tile row (144 B, 16B-aligned)

__global__ __launch_bounds__(256) void kf_fused(
    const float* __restrict__ x, const int* __restrict__ typ,
    const float* __restrict__ c, const float* __restrict__ regs,
    const u16* __restrict__ wih_bf, const u16* __restrict__ whh_bf,
    const float* __restrict__ bih, const float* __restrict__ bhh,
    const u16* __restrict__ cwih_bf, const u16* __restrict__ cwhh_bf,
    const float* __restrict__ cbih, const float* __restrict__ cbhh,
    float* __restrict__ out)
{
  __shared__ __align__(16) u16 sA[64 * SA];   // regs rows, full K=1024, bf16
  __shared__ __align__(16) u16 sH[64 * SH];   // hnew per row (H=64), bf16
  __shared__ int s_typ[64];
  __shared__ int s_order[64];
  __shared__ int s_cnt[16], s_off[16], s_cnt2[16];
  __shared__ int s_gt[24], s_gs[24], s_ge[24];
  __shared__ int s_ng;

  const int tid = threadIdx.x;
  const int b0 = blockIdx.x * 64;
  const int lane = tid & 63;
  const int w = tid >> 6;
  const int col = lane & 15;
  const int quad = lane >> 4;
  const int hidx = w * 16 + col;
  const f32x4 zero = {0.f, 0.f, 0.f, 0.f};

  // ---- stage A-tile: 64 rows x 1024 K, fully contiguous global reads ----
  {
    const float* src = regs + (size_t)b0 * 1024;
    for (int j0 = 0; j0 < 64; j0 += 8) {
      float4 v[8];
#pragma unroll
      for (int j = 0; j < 8; ++j)
        v[j] = *(const float4*)(src + (size_t)(j0 + j) * 1024 + tid * 4);
#pragma unroll
      for (int j = 0; j < 8; ++j) {
        u32x2 p; p[0] = pack2(v[j].x, v[j].y); p[1] = pack2(v[j].z, v[j].w);
        *(u32x2*)(&sA[(j0 + j) * SA + tid * 4]) = p;
      }
    }
  }

  // ---- counting sort of 64 rows by type ----
  if (tid < 16) { s_cnt[tid] = 0; s_cnt2[tid] = 0; }
  __syncthreads();
  if (tid < 64) {
    int t = typ[b0 + tid];
    s_typ[tid] = t;
    atomicAdd(&s_cnt[t], 1);
  }
  __syncthreads();
  if (tid == 0) {
    int off = 0, ng = 0;
    for (int t = 0; t < 16; ++t) {
      s_off[t] = off;
      int cnt = s_cnt[t];
      for (int base = 0; base < cnt; base += 16) {
        s_gt[ng] = t; s_gs[ng] = off + base; s_ge[ng] = off + cnt; ++ng;
      }
      off += cnt;
    }
    s_ng = ng;
  }
  __syncthreads();
  if (tid < 64) {
    int t = s_typ[tid];
    int p = s_off[t] + atomicAdd(&s_cnt2[t], 1);
    s_order[p] = tid;
  }
  __syncthreads();

  // ---- per-type GRU phase: hnew for all 64 rows -> sH ----
  const int ng = s_ng;
  for (int gi = 0; gi < ng; ++gi) {
    const int t = s_gt[gi], gs = s_gs[gi], ge = s_ge[gi];
    int p = gs + col;
    int rowm = s_order[p < ge ? p : ge - 1];

    // B fragments straight from L2 (bf16 weights in ws)
    bf16x8 bw[3][2], bh[3][2];
#pragma unroll
    for (int g = 0; g < 3; ++g) {
      const u16* pw = wih_bf + (t * 192 + g * 64 + hidx) * 64;
      const u16* ph = whh_bf + (t * 192 + g * 64 + hidx) * 64;
#pragma unroll
      for (int ks = 0; ks < 2; ++ks) {
        bw[g][ks] = *(const bf16x8*)(pw + ks * 32 + quad * 8);
        bh[g][ks] = *(const bf16x8*)(ph + ks * 32 + quad * 8);
      }
    }
    // A fragments: x direct from global, reg-slot-t from sA
    bf16x8 ax[2], ah[2];
#pragma unroll
    for (int ks = 0; ks < 2; ++ks) {
      const float* xr = x + (size_t)(b0 + rowm) * 64 + ks * 32 + quad * 8;
      ax[ks] = pack8(*(const float4*)xr, *(const float4*)(xr + 4));
      ah[ks] = *(const bf16x8*)(&sA[rowm * SA + t * 64 + ks * 32 + quad * 8]);
    }
    f32x4 agi[3], agh[3];
#pragma unroll
    for (int g = 0; g < 3; ++g) { agi[g] = zero; agh[g] = zero; }
#pragma unroll
    for (int ks = 0; ks < 2; ++ks)
#pragma unroll
      for (int g = 0; g < 3; ++g) {
        agi[g] = __builtin_amdgcn_mfma_f32_16x16x32_bf16(ax[ks], bw[g][ks], agi[g], 0, 0, 0);
        agh[g] = __builtin_amdgcn_mfma_f32_16x16x32_bf16(ah[ks], bh[g][ks], agh[g], 0, 0, 0);
      }
    float vbi[3], vbh[3];
#pragma unroll
    for (int g = 0; g < 3; ++g) {
      vbi[g] = bih[t * 192 + g * 64 + hidx];
      vbh[g] = bhh[t * 192 + g * 64 + hidx];
    }
    // D layout: col = lane&15 (n), row = quad*4 + rr (m = sorted pos)
#pragma unroll
    for (int rr = 0; rr < 4; ++rr) {
      int pp = gs + quad * 4 + rr;
      if (pp < ge) {
        int r64 = s_order[pp];
        float ir  = agi[0][rr] + vbi[0];
        float iz  = agi[1][rr] + vbi[1];
        float in_ = agi[2][rr] + vbi[2];
        float hr  = agh[0][rr] + vbh[0];
        float hz  = agh[1][rr] + vbh[1];
        float hn  = agh[2][rr] + vbh[2];
        float rg = sigf(ir + hr);
        float zg = sigf(iz + hz);
        float ngate = tanh_fast(in_ + rg * hn);
        float hold = bf2f(sA[r64 * SA + t * 64 + hidx]);
        sH[r64 * SH + hidx] = f2bf((1.f - zg) * ngate + zg * hold);
      }
    }
  }
  __syncthreads();

  // ---- core GRU: cgh = c @ cWhh^T first (K=64) ----
  f32x4 agh[4][3];
#pragma unroll
  for (int mt = 0; mt < 4; ++mt)
#pragma unroll
    for (int g = 0; g < 3; ++g) agh[mt][g] = zero;

  {
    bf16x8 bh2[3][2];
#pragma unroll
    for (int g = 0; g < 3; ++g)
#pragma unroll
      for (int ks = 0; ks < 2; ++ks)
        bh2[g][ks] = *(const bf16x8*)(cwhh_bf + (g * 64 + hidx) * 64 + ks * 32 + quad * 8);
#pragma unroll
    for (int mt = 0; mt < 4; ++mt) {
#pragma unroll
      for (int ks = 0; ks < 2; ++ks) {
        const float* cr = c + (size_t)(b0 + mt * 16 + col) * 64 + ks * 32 + quad * 8;
        bf16x8 af = pack8(*(const float4*)cr, *(const float4*)(cr + 4));
#pragma unroll
        for (int g = 0; g < 3; ++g)
          agh[mt][g] = __builtin_amdgcn_mfma_f32_16x16x32_bf16(af, bh2[g][ks], agh[mt][g], 0, 0, 0);
      }
    }
  }

  // ---- core GEMM: cgi = reg_new_flat @ cWih^T, K=1024, no barriers ----
  f32x4 agi[4][3];
#pragma unroll
  for (int mt = 0; mt < 4; ++mt)
#pragma unroll
    for (int g = 0; g < 3; ++g) agi[mt][g] = zero;

  int rowtyp[4];
#pragma unroll
  for (int mt = 0; mt < 4; ++mt) rowtyp[mt] = s_typ[mt * 16 + col];

  bf16x8 bnx[6];
#pragma unroll
  for (int g = 0; g < 3; ++g)
#pragma unroll
    for (int ks = 0; ks < 2; ++ks)
      bnx[g * 2 + ks] = *(const bf16x8*)(cwih_bf + (g * 64 + hidx) * 1024 + ks * 32 + quad * 8);

  for (int s = 0; s < 16; ++s) {
    bf16x8 bcur[6];
#pragma unroll
    for (int q = 0; q < 6; ++q) bcur[q] = bnx[q];
    if (s + 1 < 16) {
#pragma unroll
      for (int g = 0; g < 3; ++g)
#pragma unroll
        for (int ks = 0; ks < 2; ++ks)
          bnx[g * 2 + ks] = *(const bf16x8*)(cwih_bf + (g * 64 + hidx) * 1024 + (s + 1) * 64 + ks * 32 + quad * 8);
    }
#pragma unroll
    for (int ks = 0; ks < 2; ++ks) {
#pragma unroll
      for (int mt = 0; mt < 4; ++mt) {
        const int row = mt * 16 + col;
        const int koff = ks * 32 + quad * 8;
        const u16* src = (rowtyp[mt] == s) ? &sH[row * SH + koff]
                                           : &sA[row * SA + s * 64 + koff];
        bf16x8 af = *(const bf16x8*)src;
#pragma unroll
        for (int g = 0; g < 3; ++g)
          agi[mt][g] = __builtin_amdgcn_mfma_f32_16x16x32_bf16(af, bcur[g * 2 + ks], agi[mt][g], 0, 0, 0);
      }
    }
  }

  // ---- fused core-GRU epilogue ----
  float e0 = cbih[hidx], e1 = cbih[64 + hidx], e2 = cbih[128 + hidx];
  float d0 = cbhh[hidx], d1 = cbhh[64 + hidx], d2 = cbhh[128 + hidx];
#pragma unroll
  for (int mt = 0; mt < 4; ++mt) {
#pragma unroll
    for (int rr = 0; rr < 4; ++rr) {
      int row = mt * 16 + quad * 4 + rr;
      int b = b0 + row;
      float ir  = agi[mt][0][rr] + e0;
      float iz  = agi[mt][1][rr] + e1;
      float in_ = agi[mt][2][rr] + e2;
      float hr  = agh[mt][0][rr] + d0;
      float hz  = agh[mt][1][rr] + d1;
      float hn  = agh[mt][2][rr] + d2;
      float rg = sigf(ir + hr);
      float zg = sigf(iz + hz);
      float ngate = tanh_fast(in_ + rg * hn);
      float cold = c[(size_t)b * 64 + hidx];
      out[(size_t)b * 64 + hidx] = (1.f - zg) * ngate + zg * cold;
    }
  }
}

extern "C" void kernel_launch(void* const* d_in, const int* in_sizes, int n_in,
                              void* d_out, int out_size, void* d_ws, size_t ws_size,
                              hipStream_t stream) {
  const float* x    = (const float*)d_in[0];
  const int*   typ  = (const int*)d_in[1];
  const float* c    = (const float*)d_in[2];
  const float* regs = (const float*)d_in[3];
  const float* Wih  = (const float*)d_in[4];
  const float* Whh  = (const float*)d_in[5];
  const float* bih  = (const float*)d_in[6];
  const float* bhh  = (const float*)d_in[7];
  const float* cWih = (const float*)d_in[8];
  const float* cWhh = (const float*)d_in[9];
  const float* cbih = (const float*)d_in[10];
  const float* cbhh = (const float*)d_in[11];
  float* out = (float*)d_out;

  u16* wih_bf  = (u16*)d_ws;          // 196608 u16
  u16* whh_bf  = wih_bf + 196608;
  u16* cwih_bf = whh_bf + 196608;
  u16* cwhh_bf = cwih_bf + 196608;    // 12288 u16

  k0_convert<<<768, 256, 0, stream>>>(Wih, Whh, cWih, cWhh, wih_bf, whh_bf, cwih_bf, cwhh_bf);
  kf_fused<<<1024, 256, 0, stream>>>(x, typ, c, regs, wih_bf, whh_bf, bih, bhh,
                                     cwih_bf, cwhh_bf, cbih, cbhh, out);
}

// Round 3
// 474.870 us; speedup vs baseline: 1.3025x; 1.3025x over previous
//
#include <hip/hip_runtime.h>
#include <hip/hip_bf16.h>

typedef unsigned short u16;
typedef unsigned int u32;
typedef __bf16 bf16x8 __attribute__((ext_vector_type(8)));
typedef float f32x4 __attribute__((ext_vector_type(4)));

// B=65536, I=64, H=64, T=16, G=3H=192

__device__ __forceinline__ u16 f2bf(float f) {
  union { float f; u32 u; } v; v.f = f;
  u32 u = v.u;
  return (u16)((u + 0x7fffu + ((u >> 16) & 1u)) >> 16);  // RNE
}
__device__ __forceinline__ float bf2f(u16 h) {
  union { u32 u; float f; } v; v.u = ((u32)h) << 16;
  return v.f;
}
__device__ __forceinline__ u32 pk2(float a, float b) {
  union { __hip_bfloat162 h; u32 u; } v;
  v.h = __float22bfloat162_rn(float2{a, b});   // v_cvt_pk_bf16_f32 on gfx950
  return v.u;
}
__device__ __forceinline__ bf16x8 pack8(float4 a, float4 b) {
  union { u32 u[4]; bf16x8 v; } r;
  r.u[0] = pk2(a.x, a.y); r.u[1] = pk2(a.z, a.w);
  r.u[2] = pk2(b.x, b.y); r.u[3] = pk2(b.z, b.w);
  return r.v;
}
__device__ __forceinline__ float sigf(float x) { return 1.0f / (1.0f + __expf(-x)); }
__device__ __forceinline__ float tanh_fast(float x) { return 2.0f * sigf(2.0f * x) - 1.0f; }

__device__ __forceinline__ void gl_lds16(const void* g, void* l) {
  __builtin_amdgcn_global_load_lds(
      (const __attribute__((address_space(1))) unsigned int*)g,
      (__attribute__((address_space(3))) unsigned int*)l, 16, 0, 0);
}

// ---------------- K0: weight convert + zero type counters ----------------
__global__ __launch_bounds__(256) void k0_convert(
    const float* __restrict__ Wih, const float* __restrict__ Whh,
    const float* __restrict__ cWih, const float* __restrict__ cWhh,
    u16* __restrict__ wih_bf, u16* __restrict__ whh_bf,
    u16* __restrict__ cwih_bf, u16* __restrict__ cwhh_bf, int* __restrict__ gcnt)
{
  int i = blockIdx.x * 256 + threadIdx.x;
  if (blockIdx.x == 0 && threadIdx.x < 16) gcnt[threadIdx.x] = 0;
  if (i < 196608) {
    wih_bf[i]  = f2bf(Wih[i]);
    whh_bf[i]  = f2bf(Whh[i]);
    cwih_bf[i] = f2bf(cWih[i]);
  }
  if (i < 12288) cwhh_bf[i] = f2bf(cWhh[i]);
}

// ---------------- KC: compact rows by type ----------------
__global__ __launch_bounds__(256) void k_compact(
    const int* __restrict__ typ, int* __restrict__ gcnt, int* __restrict__ lists)
{
  __shared__ int cnt[16], base[16];
  const int tid = threadIdx.x;
  if (tid < 16) cnt[tid] = 0;
  __syncthreads();
  int r = blockIdx.x * 256 + tid;
  int t = typ[r];
  int rank = atomicAdd(&cnt[t], 1);
  __syncthreads();
  if (tid < 16) base[tid] = atomicAdd(&gcnt[tid], cnt[tid]);
  __syncthreads();
  lists[(size_t)t * 65536 + base[t] + rank] = r;
}

// ---------------- K1: per-type GRU -> corr (bf16, B x 192) ----------------
// corr[b] = (hnew[b] - regs[b,t]) @ cWih[:, t*64:(t+1)*64]^T
__global__ __launch_bounds__(256, 2) void k1_corr(
    const float* __restrict__ x, const float* __restrict__ regs,
    const u16* __restrict__ wih_bf, const u16* __restrict__ whh_bf,
    const float* __restrict__ bih, const float* __restrict__ bhh,
    const u16* __restrict__ cwih_bf,
    const int* __restrict__ gcnt, const int* __restrict__ lists,
    u16* __restrict__ corr)
{
  const int t = blockIdx.y;
  const int cnt = gcnt[t];
  const int ntiles = (cnt + 15) >> 4;

  const int tid = threadIdx.x;
  const int lane = tid & 63;
  const int w = tid >> 6;
  const int col = lane & 15;
  const int quad = lane >> 4;
  const int hidx = w * 16 + col;
  const f32x4 zero = {0.f, 0.f, 0.f, 0.f};

  // persistent B fragments (loaded once per block, scattered from L2)
  bf16x8 bw[3][2], bh[3][2], bc[3][2];
  float vbi[3], vbh[3];
#pragma unroll
  for (int g = 0; g < 3; ++g) {
    const u16* pw = wih_bf + ((size_t)t * 192 + g * 64 + hidx) * 64;
    const u16* ph = whh_bf + ((size_t)t * 192 + g * 64 + hidx) * 64;
    const u16* pc = cwih_bf + (size_t)(g * 64 + hidx) * 1024 + t * 64;
#pragma unroll
    for (int ks = 0; ks < 2; ++ks) {
      bw[g][ks] = *(const bf16x8*)(pw + ks * 32 + quad * 8);
      bh[g][ks] = *(const bf16x8*)(ph + ks * 32 + quad * 8);
      bc[g][ks] = *(const bf16x8*)(pc + ks * 32 + quad * 8);
    }
    vbi[g] = bih[t * 192 + g * 64 + hidx];
    vbh[g] = bhh[t * 192 + g * 64 + hidx];
  }

  __shared__ int s_rows[16];
  __shared__ __align__(16) u16 sD[16 * 72];   // delta transpose tile

  for (int tile = blockIdx.x; tile < ntiles; tile += 32) {
    __syncthreads();   // previous tile fully done
    if (tid < 16) {
      int idx = tile * 16 + tid;
      s_rows[tid] = lists[(size_t)t * 65536 + (idx < cnt ? idx : cnt - 1)];
    }
    __syncthreads();

    const int ra = s_rows[col];   // A-row for this lane's m index
    f32x4 agi[3], agh[3];
#pragma unroll
    for (int g = 0; g < 3; ++g) { agi[g] = zero; agh[g] = zero; }
#pragma unroll
    for (int ks = 0; ks < 2; ++ks) {
      const float* xr = x + (size_t)ra * 64 + ks * 32 + quad * 8;
      const float* hr = regs + (size_t)ra * 1024 + t * 64 + ks * 32 + quad * 8;
      bf16x8 ax = pack8(*(const float4*)xr, *(const float4*)(xr + 4));
      bf16x8 ah = pack8(*(const float4*)hr, *(const float4*)(hr + 4));
#pragma unroll
      for (int g = 0; g < 3; ++g) {
        agi[g] = __builtin_amdgcn_mfma_f32_16x16x32_bf16(ax, bw[g][ks], agi[g], 0, 0, 0);
        agh[g] = __builtin_amdgcn_mfma_f32_16x16x32_bf16(ah, bh[g][ks], agh[g], 0, 0, 0);
      }
    }
    // epilogue: hnew -> delta -> sD (bf16, A-layout rows)
#pragma unroll
    for (int rr = 0; rr < 4; ++rr) {
      int m = quad * 4 + rr;
      if (tile * 16 + m < cnt) {
        int r2 = s_rows[m];
        float ir  = agi[0][rr] + vbi[0];
        float iz  = agi[1][rr] + vbi[1];
        float in_ = agi[2][rr] + vbi[2];
        float hr  = agh[0][rr] + vbh[0];
        float hz  = agh[1][rr] + vbh[1];
        float hn  = agh[2][rr] + vbh[2];
        float rg = sigf(ir + hr);
        float zg = sigf(iz + hz);
        float ng = tanh_fast(in_ + rg * hn);
        float hold = regs[(size_t)r2 * 1024 + t * 64 + hidx];
        float hnew = (1.f - zg) * ng + zg * hold;
        sD[m * 72 + hidx] = f2bf(hnew - hold);
      }
    }
    __syncthreads();

    // corr GEMM: delta (16x64) @ bc^T
    f32x4 acr[3];
#pragma unroll
    for (int g = 0; g < 3; ++g) acr[g] = zero;
#pragma unroll
    for (int ks = 0; ks < 2; ++ks) {
      bf16x8 ad = *(const bf16x8*)(&sD[col * 72 + ks * 32 + quad * 8]);
#pragma unroll
      for (int g = 0; g < 3; ++g)
        acr[g] = __builtin_amdgcn_mfma_f32_16x16x32_bf16(ad, bc[g][ks], acr[g], 0, 0, 0);
    }
#pragma unroll
    for (int rr = 0; rr < 4; ++rr) {
      int m = quad * 4 + rr;
      if (tile * 16 + m < cnt) {
        int r2 = s_rows[m];
#pragma unroll
        for (int g = 0; g < 3; ++g)
          corr[(size_t)r2 * 192 + g * 64 + hidx] = f2bf(acr[g][rr]);
      }
    }
  }
}

// ---------------- K2: streaming GEMM + core GRU ----------------
// 64 rows/block, grid 1024, 16 K-chunks of 64, double-buffered global_load_lds,
// XOR-swizzled LDS (swizzle applied on the per-lane GLOBAL address).
__global__ __launch_bounds__(256, 2) void k2_core(
    const float* __restrict__ regs, const float* __restrict__ c,
    const u16* __restrict__ cwih_bf, const u16* __restrict__ cwhh_bf,
    const float* __restrict__ cbih, const float* __restrict__ cbhh,
    const u16* __restrict__ corr, float* __restrict__ out)
{
  __shared__ __align__(16) float sA[2][4096];   // 64 rows x 64 f32, 16 KB each
  __shared__ __align__(16) u16  sB[2][12288];   // 192 rows x 64 bf16, 24 KB each

  const int tid = threadIdx.x;
  const int b0 = blockIdx.x * 64;
  const int lane = tid & 63;
  const int wv = tid >> 6;
  const int col = lane & 15;
  const int quad = lane >> 4;
  const int hidx = wv * 16 + col;
  const f32x4 zero = {0.f, 0.f, 0.f, 0.f};

  // --- stage chunk 0 ---
  {
#pragma unroll
    for (int s = 0; s < 4; ++s) {
      int i = s * 4 + wv;
      int r = i * 4 + (lane >> 4);
      int grp = lane & 15;
      gl_lds16(regs + (size_t)(b0 + r) * 1024 + ((grp ^ (r & 15)) << 2), &sA[0][i * 256]);
    }
#pragma unroll
    for (int s = 0; s < 6; ++s) {
      int j = s * 4 + wv;
      int n = j * 8 + (lane >> 3);
      int grp = lane & 7;
      gl_lds16(cwih_bf + (size_t)n * 1024 + ((grp ^ (n & 7)) << 3), &sB[0][j * 512]);
    }
  }

  // --- cgh = c @ cWhh^T (K=64), direct from global, overlaps stage-0 latency ---
  f32x4 agh[4][3];
#pragma unroll
  for (int mt = 0; mt < 4; ++mt)
#pragma unroll
    for (int g = 0; g < 3; ++g) agh[mt][g] = zero;
#pragma unroll
  for (int ks = 0; ks < 2; ++ks) {
    bf16x8 bh2[3];
#pragma unroll
    for (int g = 0; g < 3; ++g)
      bh2[g] = *(const bf16x8*)(cwhh_bf + (size_t)(g * 64 + hidx) * 64 + ks * 32 + quad * 8);
#pragma unroll
    for (int mt = 0; mt < 4; ++mt) {
      const float* cr = c + (size_t)(b0 + mt * 16 + col) * 64 + ks * 32 + quad * 8;
      bf16x8 af = pack8(*(const float4*)cr, *(const float4*)(cr + 4));
#pragma unroll
      for (int g = 0; g < 3; ++g)
        agh[mt][g] = __builtin_amdgcn_mfma_f32_16x16x32_bf16(af, bh2[g], agh[mt][g], 0, 0, 0);
    }
  }

  // --- main K-loop ---
  f32x4 agi[4][3];
#pragma unroll
  for (int mt = 0; mt < 4; ++mt)
#pragma unroll
    for (int g = 0; g < 3; ++g) agi[mt][g] = zero;

  for (int kc = 0; kc < 16; ++kc) {
    __syncthreads();   // drains stage of current buffer; prior reads of next buffer done
    if (kc < 15) {
      float* sAn = sA[(kc + 1) & 1];
      u16*   sBn = sB[(kc + 1) & 1];
#pragma unroll
      for (int s = 0; s < 4; ++s) {
        int i = s * 4 + wv;
        int r = i * 4 + (lane >> 4);
        int grp = lane & 15;
        gl_lds16(regs + (size_t)(b0 + r) * 1024 + (kc + 1) * 64 + ((grp ^ (r & 15)) << 2),
                 sAn + i * 256);
      }
#pragma unroll
      for (int s = 0; s < 6; ++s) {
        int j = s * 4 + wv;
        int n = j * 8 + (lane >> 3);
        int grp = lane & 7;
        gl_lds16(cwih_bf + (size_t)n * 1024 + (kc + 1) * 64 + ((grp ^ (n & 7)) << 3),
                 sBn + j * 512);
      }
    }
    const float* sAc = sA[kc & 1];
    const u16*   sBc = sB[kc & 1];
#pragma unroll
    for (int ks = 0; ks < 2; ++ks) {
      bf16x8 bfr[3];
#pragma unroll
      for (int g = 0; g < 3; ++g) {
        int n = g * 64 + hidx;
        int grp = ks * 4 + quad;
        bfr[g] = *(const bf16x8*)(sBc + n * 64 + ((grp ^ (n & 7)) << 3));
      }
#pragma unroll
      for (int mt = 0; mt < 4; ++mt) {
        int r = mt * 16 + col;
        int g0 = ks * 8 + quad * 2;
        float4 q0 = *(const float4*)(sAc + r * 64 + (((g0    ) ^ (r & 15)) << 2));
        float4 q1 = *(const float4*)(sAc + r * 64 + (((g0 + 1) ^ (r & 15)) << 2));
        bf16x8 af = pack8(q0, q1);
#pragma unroll
        for (int g = 0; g < 3; ++g)
          agi[mt][g] = __builtin_amdgcn_mfma_f32_16x16x32_bf16(af, bfr[g], agi[mt][g], 0, 0, 0);
      }
    }
  }

  // --- fused core-GRU epilogue ---
  float e0 = cbih[hidx], e1 = cbih[64 + hidx], e2 = cbih[128 + hidx];
  float d0 = cbhh[hidx], d1 = cbhh[64 + hidx], d2 = cbhh[128 + hidx];
#pragma unroll
  for (int mt = 0; mt < 4; ++mt) {
#pragma unroll
    for (int rr = 0; rr < 4; ++rr) {
      int row = mt * 16 + quad * 4 + rr;
      size_t b = (size_t)(b0 + row);
      float ir  = agi[mt][0][rr] + e0 + bf2f(corr[b * 192 + hidx]);
      float iz  = agi[mt][1][rr] + e1 + bf2f(corr[b * 192 + 64 + hidx]);
      float in_ = agi[mt][2][rr] + e2 + bf2f(corr[b * 192 + 128 + hidx]);
      float hr  = agh[mt][0][rr] + d0;
      float hz  = agh[mt][1][rr] + d1;
      float hn  = agh[mt][2][rr] + d2;
      float rg = sigf(ir + hr);
      float zg = sigf(iz + hz);
      float ng = tanh_fast(in_ + rg * hn);
      float cold = c[b * 64 + hidx];
      out[b * 64 + hidx] = (1.f - zg) * ng + zg * cold;
    }
  }
}

extern "C" void kernel_launch(void* const* d_in, const int* in_sizes, int n_in,
                              void* d_out, int out_size, void* d_ws, size_t ws_size,
                              hipStream_t stream) {
  const float* x    = (const float*)d_in[0];
  const int*   typ  = (const int*)d_in[1];
  const float* c    = (const float*)d_in[2];
  const float* regs = (const float*)d_in[3];
  const float* Wih  = (const float*)d_in[4];
  const float* Whh  = (const float*)d_in[5];
  const float* bih  = (const float*)d_in[6];
  const float* bhh  = (const float*)d_in[7];
  const float* cWih = (const float*)d_in[8];
  const float* cWhh = (const float*)d_in[9];
  const float* cbih = (const float*)d_in[10];
  const float* cbhh = (const float*)d_in[11];
  float* out = (float*)d_out;

  char* ws = (char*)d_ws;
  u16* wih_bf  = (u16*)(ws + 0);            // 393216 B
  u16* whh_bf  = (u16*)(ws + 393216);       // 393216 B
  u16* cwih_bf = (u16*)(ws + 786432);       // 393216 B
  u16* cwhh_bf = (u16*)(ws + 1179648);      // 24576 B
  int* gcnt    = (int*)(ws + 1204224);      // 64 B
  int* lists   = (int*)(ws + 1204288);      // 4 MB
  u16* corr    = (u16*)(ws + 5398592);      // 25165824 B  (total ~30.6 MB)

  k0_convert<<<768, 256, 0, stream>>>(Wih, Whh, cWih, cWhh,
                                      wih_bf, whh_bf, cwih_bf, cwhh_bf, gcnt);
  k_compact<<<256, 256, 0, stream>>>(typ, gcnt, lists);
  k1_corr<<<dim3(32, 16), 256, 0, stream>>>(x, regs, wih_bf, whh_bf, bih, bhh,
                                            cwih_bf, gcnt, lists, corr);
  k2_core<<<1024, 256, 0, stream>>>(regs, c, cwih_bf, cwhh_bf, cbih, cbhh, corr, out);
}